// Round 4
// baseline (7958.064 us; speedup 1.0000x reference)
//
#include <hip/hip_runtime.h>

typedef unsigned int uint;
typedef unsigned short ushort;

#define B_  2
#define NA  2048
#define NN  48
#define G_  50
#define F_  128
#define NK  49   // Nn + 1 (self)
#define NROW (B_ * NA * NN)   // 196608 flat filter rows

__device__ __forceinline__ float ssp(float z) {  // softplus(z) - ln2, stable
  return fmaxf(z, 0.f) + log1pf(__expf(-fabsf(z))) - 0.69314718055994531f;
}

// =====================================================================
// K1: filter MLP over flat rows R = a*NN + n.
//     out_W[R,:] = (ssp((2*f_ij[R,:]-1) @ Wf1 + b1) @ Wf2 + b2) * C(r_ij[R])
//     64 rows per block; weights read once per block (L3-resident).
// =====================================================================
struct __align__(16) SmemA {
  float ft[64 * 56];    // (2*f_ij-1), row stride 56 (16B-aligned float4)
  float h1[64 * 132];   // ssp(layer1), row stride 132 (16B-aligned float4)
  float C[64];          // cosine cutoff per row
};  // 48384 B -> 3 blocks/CU

extern "C" __global__ __launch_bounds__(256, 3)
void filter_kernel(const float* __restrict__ fij, const float* __restrict__ r_ij,
                   const float* __restrict__ Wf1, const float* __restrict__ bf1,
                   const float* __restrict__ Wf2, const float* __restrict__ bf2p,
                   float* __restrict__ out_W)
{
  __shared__ SmemA sm;
  const int t = threadIdx.x;
  const int f = t & 127, h = t >> 7;
  const size_t Rb = (size_t)blockIdx.x * 64;

  // ---- stage (2*f_ij-1) tile [64][50] and C ----
  {
    const int col = t & 63, r4 = t >> 6;
    #pragma unroll
    for (int rr = 0; rr < 16; ++rr) {
      int row = rr * 4 + r4;
      if (col < G_)
        sm.ft[row * 56 + col] = 2.f * fij[(Rb + row) * G_ + col] - 1.f;
    }
  }
  if (t < 64) {
    float r = r_ij[Rb + t];
    sm.C[t] = (r < 5.0f) ? 0.5f * (cosf(0.62831853071795864769f * r) + 1.0f) : 0.0f;
  }
  __syncthreads();

  // ---- P1: h1 = ssp(ft @ Wf1 + b1); thread (f,h) does rows h*32+j ----
  {
    float wr[50];
    #pragma unroll
    for (int g = 0; g < G_; ++g) wr[g] = Wf1[(size_t)g * F_ + f];
    float bb = bf1[f];
    #pragma unroll 4
    for (int j = 0; j < 32; ++j) {
      int r = h * 32 + j;
      const float* fr = &sm.ft[r * 56];
      float s = bb;
      #pragma unroll
      for (int g4 = 0; g4 < 12; ++g4) {        // 48 via float4
        float4 v = *(const float4*)(fr + g4 * 4);
        s += v.x * wr[g4 * 4] + v.y * wr[g4 * 4 + 1]
           + v.z * wr[g4 * 4 + 2] + v.w * wr[g4 * 4 + 3];
      }
      s += fr[48] * wr[48] + fr[49] * wr[49];
      sm.h1[r * 132 + f] = ssp(s);
    }
  }
  __syncthreads();

  // ---- P2: W = (h1 @ Wf2 + b2) * C; 32 rows per thread, k in 4 chunks ----
  {
    float acc[32];
    float b2 = bf2p[f];
    #pragma unroll
    for (int j = 0; j < 32; ++j) acc[j] = b2;
    #pragma unroll
    for (int kc = 0; kc < 4; ++kc) {
      float wv[32];
      #pragma unroll
      for (int kk = 0; kk < 32; ++kk) wv[kk] = Wf2[(size_t)(kc * 32 + kk) * F_ + f];
      #pragma unroll
      for (int j = 0; j < 32; ++j) {
        const float4* hr = (const float4*)&sm.h1[(h * 32 + j) * 132 + kc * 32];
        #pragma unroll
        for (int q = 0; q < 8; ++q) {          // b128 broadcast reads
          float4 v = hr[q];
          acc[j] += v.x * wv[q * 4] + v.y * wv[q * 4 + 1]
                  + v.z * wv[q * 4 + 2] + v.w * wv[q * 4 + 3];
        }
      }
    }
    #pragma unroll
    for (int j = 0; j < 32; ++j) {
      int r = h * 32 + j;
      out_W[(Rb + r) * F_ + f] = acc[j] * sm.C[r];
    }
  }
}

// =====================================================================
// K2: per-atom gather + q/k/v attention; W read back as a stream.
// =====================================================================
struct __align__(16) SmemB {
  float y[NK * 128];   // y_full [49][128]
  float q[128];        // q, later reused as m
  float qk[128];       // Wk @ q
  float attn[64];
  float red[256];
  int   nbr[48];
};  // 27648 B -> 5 blocks/CU (LDS)

extern "C" __global__ __launch_bounds__(256, 4)
void attn_kernel(const float* __restrict__ x, const int* __restrict__ nbr,
                 const int* __restrict__ pmask, const float* __restrict__ Wg,
                 const float* __restrict__ Wq, const float* __restrict__ Wk,
                 const float* __restrict__ Wv, const float* __restrict__ Wo,
                 const float* __restrict__ bo,
                 float* __restrict__ out_m)
{
  __shared__ SmemB sm;
  const int t = threadIdx.x;
  const int f = t & 127, h = t >> 7;
  const int lane = t & 63, w = t >> 6;
  const int a = blockIdx.x;
  const int b = a >> 11, i = a & 2047;
  const size_t base_nn = (size_t)a * NN;

  if (t < NN) sm.nbr[t] = nbr[base_nn + t];
  __syncthreads();

  // ---- gather y_full = [self, x[neighbors]] ----
  for (int row = w; row < NK; row += 4) {
    int src = (row == 0) ? i : sm.nbr[row - 1];
    const float2* xr = (const float2*)(x + ((size_t)b * NA + src) * F_);
    *(float2*)&sm.y[row * F_ + lane * 2] = xr[lane];
  }
  __syncthreads();

  // ---- q = x_self @ Wq ----
  {
    float p = 0.f;
    #pragma unroll 8
    for (int c = h * 64; c < h * 64 + 64; ++c)
      p += sm.y[c] * Wq[(size_t)c * F_ + f];
    sm.red[h * F_ + f] = p;
  }
  __syncthreads();
  if (t < F_) sm.q[t] = sm.red[t] + sm.red[F_ + t];
  __syncthreads();

  // ---- qk = Wk @ q (row-dot via wave shuffle) ----
  for (int fo = w; fo < F_; fo += 4) {
    float2 ww = *(const float2*)(Wk + (size_t)fo * F_ + lane * 2);
    float p = ww.x * sm.q[lane * 2] + ww.y * sm.q[lane * 2 + 1];
    #pragma unroll
    for (int o = 32; o; o >>= 1) p += __shfl_xor(p, o);
    if (lane == 0) sm.qk[fo] = p;
  }
  __syncthreads();

  // ---- scores + masked softmax ----
  {
    int n = lane;
    float p = 0.f;
    if (n < NK) {
      const float* yr = &sm.y[n * F_ + w * 32];
      const float* qr = &sm.qk[w * 32];
      #pragma unroll
      for (int k = 0; k < 32; ++k) {
        int c = (k + n) & 31;   // lane-rotated: bank-conflict-free
        p += yr[c] * qr[c];
      }
    }
    sm.red[w * 64 + n] = p;
  }
  __syncthreads();
  if (t < 64) {
    float s = -1e30f;
    if (t < NK) {
      s = (sm.red[t] + sm.red[64 + t] + sm.red[128 + t] + sm.red[192 + t])
          * 0.08838834764831845f;   // 1/sqrt(128)
      if (t >= 1 && pmask[base_nn + t - 1] == 0) s = -1e9f;
    }
    float mx = s;
    #pragma unroll
    for (int o = 32; o; o >>= 1) mx = fmaxf(mx, __shfl_xor(mx, o));
    float ev = (t < NK) ? __expf(s - mx) : 0.f;
    float sum = ev;
    #pragma unroll
    for (int o = 32; o; o >>= 1) sum += __shfl_xor(sum, o);
    if (t < NK) sm.attn[t] = ev / sum;
  }
  __syncthreads();

  // ---- m = sum_n attn[n]*mod[n]*(y_n @ Wv), fused ----
  {
    const int n0 = h ? 25 : 0;
    const int cnt = h ? 24 : 25;
    float vn[25];
    #pragma unroll
    for (int j = 0; j < 25; ++j) vn[j] = 0.f;
    #pragma unroll
    for (int kc = 0; kc < 4; ++kc) {
      float wr[32];
      #pragma unroll
      for (int kk = 0; kk < 32; ++kk) wr[kk] = Wv[(size_t)(kc * 32 + kk) * F_ + f];
      #pragma unroll
      for (int j = 0; j < 25; ++j) {
        if (j < cnt) {
          const float4* yr = (const float4*)&sm.y[(n0 + j) * F_ + kc * 32];
          #pragma unroll
          for (int q = 0; q < 8; ++q) {        // b128 broadcast reads
            float4 v = yr[q];
            vn[j] += v.x * wr[q * 4] + v.y * wr[q * 4 + 1]
                   + v.z * wr[q * 4 + 2] + v.w * wr[q * 4 + 3];
          }
        }
      }
    }
    float msum = 0.f;
    #pragma unroll
    for (int j = 0; j < 25; ++j) {
      if (j < cnt) {
        int n = n0 + j;
        float coef = sm.attn[n];
        if (n > 0) coef *= Wg[(base_nn + n - 1) * F_ + f];  // stream read of W
        msum += coef * vn[j];
      }
    }
    sm.red[h * F_ + f] = msum;
  }
  __syncthreads();
  if (t < F_) sm.q[t] = sm.red[t] + sm.red[F_ + t];   // reuse q[] as m[]
  __syncthreads();

  // ---- out_m = ssp(m @ Wo + bo) ----
  {
    float p = 0.f;
    #pragma unroll 8
    for (int c = h * 64; c < h * 64 + 64; ++c)
      p += sm.q[c] * Wo[(size_t)c * F_ + f];
    sm.red[h * F_ + f] = p;
  }
  __syncthreads();
  if (t < F_) {
    float v = sm.red[t] + sm.red[F_ + t] + bo[t];
    out_m[(size_t)a * F_ + t] = ssp(v);
  }
}

extern "C" void kernel_launch(void* const* d_in, const int* in_sizes, int n_in,
                              void* d_out, int out_size, void* d_ws, size_t ws_size,
                              hipStream_t stream) {
  // inputs: 0=e(unused) 1=x 2=t(unused) 3=r_ij 4=neighbors 5=pairwise_mask 6=f_ij
  //         7=Wf1 8=bf1 9=Wf2 10=bf2 11=Wq 12=Wk 13=Wv 14=Wo 15=bo
  const float* x   = (const float*)d_in[1];
  const float* r   = (const float*)d_in[3];
  const int*  nbr  = (const int*)d_in[4];
  const int*  pmk  = (const int*)d_in[5];
  const float* fij = (const float*)d_in[6];
  const float* Wf1 = (const float*)d_in[7];
  const float* bf1 = (const float*)d_in[8];
  const float* Wf2 = (const float*)d_in[9];
  const float* bf2p= (const float*)d_in[10];
  const float* Wq  = (const float*)d_in[11];
  const float* Wk  = (const float*)d_in[12];
  const float* Wv  = (const float*)d_in[13];
  const float* Wo  = (const float*)d_in[14];
  const float* bo  = (const float*)d_in[15];
  float* out_m = (float*)d_out;                       // [B,Na,F]
  float* out_W = out_m + (size_t)B_ * NA * F_;        // [B,Na,Nn,F]

  hipLaunchKernelGGL(filter_kernel, dim3(NROW / 64), dim3(256), 0, stream,
                     fij, r, Wf1, bf1, Wf2, bf2p, out_W);
  hipLaunchKernelGGL(attn_kernel, dim3(B_ * NA), dim3(256), 0, stream,
                     x, nbr, pmk, out_W, Wq, Wk, Wv, Wo, bo, out_m);
}

// Round 5
// 481.216 us; speedup vs baseline: 16.5374x; 16.5374x over previous
//
#include <hip/hip_runtime.h>

typedef unsigned int uint;
typedef unsigned short ushort;

#define B_  2
#define NA  2048
#define NN  48
#define G_  50
#define F_  128
#define NK  49   // Nn + 1 (self)
#define NROW (B_ * NA * NN)   // 196608 flat filter rows
#define NAT  (B_ * NA)        // 4096 atoms

__device__ __forceinline__ float ssp(float z) {  // softplus(z) - ln2, stable
  return fmaxf(z, 0.f) + log1pf(__expf(-fabsf(z))) - 0.69314718055994531f;
}

// =====================================================================
// K0: QKV = x @ {Wq,Wk,Wv}; flat GEMM, 32 rows/block, blockIdx.y picks mat.
// =====================================================================
extern "C" __global__ __launch_bounds__(256, 4)
void qkv_kernel(const float* __restrict__ x,
                const float* __restrict__ Wq, const float* __restrict__ Wk,
                const float* __restrict__ Wv,
                float* __restrict__ Qo, float* __restrict__ Ko, float* __restrict__ Vo)
{
  __shared__ float xs[32 * 128];
  const int t = threadIdx.x;
  const int f = t & 127, h = t >> 7;
  const size_t Rb = (size_t)blockIdx.x * 32;
  const float* W = (blockIdx.y == 0) ? Wq : (blockIdx.y == 1) ? Wk : Wv;
  float* O = (blockIdx.y == 0) ? Qo : (blockIdx.y == 1) ? Ko : Vo;

  // stage x tile [32][128]
  {
    const float4* src = (const float4*)(x + Rb * F_);
    float4* dst = (float4*)xs;
    #pragma unroll
    for (int k = 0; k < 4; ++k) dst[t + 256 * k] = src[t + 256 * k];
  }
  __syncthreads();

  float acc[16];
  #pragma unroll
  for (int j = 0; j < 16; ++j) acc[j] = 0.f;
  #pragma unroll
  for (int kc = 0; kc < 4; ++kc) {
    float wr[32];
    #pragma unroll
    for (int kk = 0; kk < 32; ++kk) wr[kk] = W[(size_t)(kc * 32 + kk) * F_ + f];
    #pragma unroll
    for (int j = 0; j < 16; ++j) {
      const float4* xr = (const float4*)&xs[(h * 16 + j) * 128 + kc * 32];
      #pragma unroll
      for (int q = 0; q < 8; ++q) {   // wave-uniform b128 broadcasts
        float4 v = xr[q];
        acc[j] += v.x * wr[q * 4] + v.y * wr[q * 4 + 1]
                + v.z * wr[q * 4 + 2] + v.w * wr[q * 4 + 3];
      }
    }
  }
  #pragma unroll
  for (int j = 0; j < 16; ++j)
    O[(Rb + h * 16 + j) * F_ + f] = acc[j];
}

// =====================================================================
// K1: filter MLP over flat rows (unchanged from R4 — measured ~0.45ms).
// =====================================================================
struct __align__(16) SmemA {
  float ft[64 * 56];
  float h1[64 * 132];
  float C[64];
};  // 48384 B -> 3 blocks/CU

extern "C" __global__ __launch_bounds__(256, 3)
void filter_kernel(const float* __restrict__ fij, const float* __restrict__ r_ij,
                   const float* __restrict__ Wf1, const float* __restrict__ bf1,
                   const float* __restrict__ Wf2, const float* __restrict__ bf2p,
                   float* __restrict__ out_W)
{
  __shared__ SmemA sm;
  const int t = threadIdx.x;
  const int f = t & 127, h = t >> 7;
  const size_t Rb = (size_t)blockIdx.x * 64;

  {
    const int col = t & 63, r4 = t >> 6;
    #pragma unroll
    for (int rr = 0; rr < 16; ++rr) {
      int row = rr * 4 + r4;
      if (col < G_)
        sm.ft[row * 56 + col] = 2.f * fij[(Rb + row) * G_ + col] - 1.f;
    }
  }
  if (t < 64) {
    float r = r_ij[Rb + t];
    sm.C[t] = (r < 5.0f) ? 0.5f * (cosf(0.62831853071795864769f * r) + 1.0f) : 0.0f;
  }
  __syncthreads();

  {
    float wr[50];
    #pragma unroll
    for (int g = 0; g < G_; ++g) wr[g] = Wf1[(size_t)g * F_ + f];
    float bb = bf1[f];
    #pragma unroll 4
    for (int j = 0; j < 32; ++j) {
      int r = h * 32 + j;
      const float* fr = &sm.ft[r * 56];
      float s = bb;
      #pragma unroll
      for (int g4 = 0; g4 < 12; ++g4) {
        float4 v = *(const float4*)(fr + g4 * 4);
        s += v.x * wr[g4 * 4] + v.y * wr[g4 * 4 + 1]
           + v.z * wr[g4 * 4 + 2] + v.w * wr[g4 * 4 + 3];
      }
      s += fr[48] * wr[48] + fr[49] * wr[49];
      sm.h1[r * 132 + f] = ssp(s);
    }
  }
  __syncthreads();

  {
    float acc[32];
    float b2 = bf2p[f];
    #pragma unroll
    for (int j = 0; j < 32; ++j) acc[j] = b2;
    #pragma unroll
    for (int kc = 0; kc < 4; ++kc) {
      float wv[32];
      #pragma unroll
      for (int kk = 0; kk < 32; ++kk) wv[kk] = Wf2[(size_t)(kc * 32 + kk) * F_ + f];
      #pragma unroll
      for (int j = 0; j < 32; ++j) {
        const float4* hr = (const float4*)&sm.h1[(h * 32 + j) * 132 + kc * 32];
        #pragma unroll
        for (int q = 0; q < 8; ++q) {
          float4 v = hr[q];
          acc[j] += v.x * wv[q * 4] + v.y * wv[q * 4 + 1]
                  + v.z * wv[q * 4 + 2] + v.w * wv[q * 4 + 3];
        }
      }
    }
    #pragma unroll
    for (int j = 0; j < 32; ++j) {
      int r = h * 32 + j;
      out_W[(Rb + r) * F_ + f] = acc[j] * sm.C[r];
    }
  }
}

// =====================================================================
// K2: wave-per-atom attention. No LDS, no barriers. Gathers precomputed
//     K/V rows (2MB tables), scores via cross-lane reduce, softmax in
//     registers, filter-modulated weighted sum -> m_pre.
// =====================================================================
extern "C" __global__ __launch_bounds__(256, 4)
void attn_kernel(const float* __restrict__ Q, const float* __restrict__ K,
                 const float* __restrict__ V, const float* __restrict__ Wg,
                 const int* __restrict__ nbr, const int* __restrict__ pmask,
                 float* __restrict__ m_pre)
{
  const int t = threadIdx.x;
  const int lane = t & 63, w = t >> 6;
  const int a = blockIdx.x * 4 + w;          // atom id
  const int b = a >> 11, i = a & 2047;
  const size_t base_nn = (size_t)a * NN;

  // per-lane preload of neighbor ids / masks (lane n holds entry n)
  int nbrv = (lane < NN) ? nbr[base_nn + lane] : 0;
  int pmv  = (lane < NN) ? pmask[base_nn + lane] : 1;

  float2 q2 = *(const float2*)(Q + (size_t)a * F_ + lane * 2);

  // ---- scores: s_n = q . K[src_n] / sqrt(F), masked ----
  float s_lane = -1e30f;
  #pragma unroll
  for (int n = 0; n < NK; ++n) {
    int src = (n == 0) ? i : __shfl(nbrv, n - 1);
    float2 k2 = *(const float2*)(K + ((size_t)b * NA + src) * F_ + lane * 2);
    float p = q2.x * k2.x + q2.y * k2.y;
    #pragma unroll
    for (int o = 32; o; o >>= 1) p += __shfl_xor(p, o);
    p *= 0.08838834764831845f;                 // 1/sqrt(128)
    if (n > 0 && __shfl(pmv, n - 1) == 0) p = -1e9f;
    if (lane == n) s_lane = p;
  }

  // ---- softmax across lanes 0..48 ----
  float mx = s_lane;
  #pragma unroll
  for (int o = 32; o; o >>= 1) mx = fmaxf(mx, __shfl_xor(mx, o));
  float ev = (lane < NK) ? __expf(s_lane - mx) : 0.f;
  float sum = ev;
  #pragma unroll
  for (int o = 32; o; o >>= 1) sum += __shfl_xor(sum, o);
  float attn_l = ev / sum;                     // lane n holds attn[n]

  // ---- m = sum_n attn[n] * (n? W[n-1]*V[src] : V[i]) ----
  float2 acc = {0.f, 0.f};
  #pragma unroll 8
  for (int n = 0; n < NK; ++n) {
    float an = __shfl(attn_l, n);
    int src = (n == 0) ? i : __shfl(nbrv, n - 1);
    float2 v2 = *(const float2*)(V + ((size_t)b * NA + src) * F_ + lane * 2);
    float2 w2 = {1.f, 1.f};
    if (n > 0) w2 = *(const float2*)(Wg + (base_nn + n - 1) * F_ + lane * 2);
    acc.x += an * w2.x * v2.x;
    acc.y += an * w2.y * v2.y;
  }
  *(float2*)(m_pre + (size_t)a * F_ + lane * 2) = acc;
}

// =====================================================================
// K3: out_m = ssp(m_pre @ Wo + bo); flat GEMM, 32 rows/block.
// =====================================================================
extern "C" __global__ __launch_bounds__(256, 4)
void out_kernel(const float* __restrict__ m_pre, const float* __restrict__ Wo,
                const float* __restrict__ bo, float* __restrict__ out_m)
{
  __shared__ float xs[32 * 128];
  const int t = threadIdx.x;
  const int f = t & 127, h = t >> 7;
  const size_t Rb = (size_t)blockIdx.x * 32;

  {
    const float4* src = (const float4*)(m_pre + Rb * F_);
    float4* dst = (float4*)xs;
    #pragma unroll
    for (int k = 0; k < 4; ++k) dst[t + 256 * k] = src[t + 256 * k];
  }
  __syncthreads();

  float acc[16];
  float bb = bo[f];
  #pragma unroll
  for (int j = 0; j < 16; ++j) acc[j] = bb;
  #pragma unroll
  for (int kc = 0; kc < 4; ++kc) {
    float wr[32];
    #pragma unroll
    for (int kk = 0; kk < 32; ++kk) wr[kk] = Wo[(size_t)(kc * 32 + kk) * F_ + f];
    #pragma unroll
    for (int j = 0; j < 16; ++j) {
      const float4* xr = (const float4*)&xs[(h * 16 + j) * 128 + kc * 32];
      #pragma unroll
      for (int q = 0; q < 8; ++q) {
        float4 v = xr[q];
        acc[j] += v.x * wr[q * 4] + v.y * wr[q * 4 + 1]
                + v.z * wr[q * 4 + 2] + v.w * wr[q * 4 + 3];
      }
    }
  }
  #pragma unroll
  for (int j = 0; j < 16; ++j)
    out_m[(Rb + h * 16 + j) * F_ + f] = ssp(acc[j]);
}

extern "C" void kernel_launch(void* const* d_in, const int* in_sizes, int n_in,
                              void* d_out, int out_size, void* d_ws, size_t ws_size,
                              hipStream_t stream) {
  // inputs: 0=e(unused) 1=x 2=t(unused) 3=r_ij 4=neighbors 5=pairwise_mask 6=f_ij
  //         7=Wf1 8=bf1 9=Wf2 10=bf2 11=Wq 12=Wk 13=Wv 14=Wo 15=bo
  const float* x   = (const float*)d_in[1];
  const float* r   = (const float*)d_in[3];
  const int*  nbr  = (const int*)d_in[4];
  const int*  pmk  = (const int*)d_in[5];
  const float* fij = (const float*)d_in[6];
  const float* Wf1 = (const float*)d_in[7];
  const float* bf1 = (const float*)d_in[8];
  const float* Wf2 = (const float*)d_in[9];
  const float* bf2p= (const float*)d_in[10];
  const float* Wq  = (const float*)d_in[11];
  const float* Wk  = (const float*)d_in[12];
  const float* Wv  = (const float*)d_in[13];
  const float* Wo  = (const float*)d_in[14];
  const float* bo  = (const float*)d_in[15];
  float* out_m = (float*)d_out;                       // [B,Na,F]
  float* out_W = out_m + (size_t)NAT * F_;            // [B,Na,Nn,F]

  // workspace: Q | K | V | m_pre  (4 x 2MB = 8MB)
  float* Qs = (float*)d_ws;
  float* Ks = Qs + (size_t)NAT * F_;
  float* Vs = Ks + (size_t)NAT * F_;
  float* Ms = Vs + (size_t)NAT * F_;

  hipLaunchKernelGGL(qkv_kernel, dim3(NAT / 32, 3), dim3(256), 0, stream,
                     x, Wq, Wk, Wv, Qs, Ks, Vs);
  hipLaunchKernelGGL(filter_kernel, dim3(NROW / 64), dim3(256), 0, stream,
                     fij, r, Wf1, bf1, Wf2, bf2p, out_W);
  hipLaunchKernelGGL(attn_kernel, dim3(NAT / 4), dim3(256), 0, stream,
                     Qs, Ks, Vs, out_W, nbr, pmk, Ms);
  hipLaunchKernelGGL(out_kernel, dim3(NAT / 32), dim3(256), 0, stream,
                     Ms, Wo, bo, out_m);
}

// Round 6
// 311.953 us; speedup vs baseline: 25.5104x; 1.5426x over previous
//
#include <hip/hip_runtime.h>

typedef unsigned int uint;
typedef unsigned short ushort;

#define B_  2
#define NA  2048
#define NN  48
#define G_  50
#define F_  128
#define NK  49   // Nn + 1 (self)
#define NROW (B_ * NA * NN)   // 196608 flat filter rows
#define NAT  (B_ * NA)        // 4096 atoms

typedef short short8 __attribute__((ext_vector_type(8)));
typedef float floatx4 __attribute__((ext_vector_type(4)));

__device__ __forceinline__ float ssp(float z) {  // softplus(z) - ln2, stable
  return fmaxf(z, 0.f) + log1pf(__expf(-fabsf(z))) - 0.69314718055994531f;
}
__device__ __forceinline__ ushort f2bf(float x) {  // RNE
  union { float f; uint u; } v; v.f = x;
  uint u = v.u;
  u += 0x7fffu + ((u >> 16) & 1u);
  return (ushort)(u >> 16);
}

// =====================================================================
// P: one-time (per launch) weight prep: transposed bf16 copies for MFMA
//    B-fragments ([n][k], k contiguous). Wf1t K-padded 50->64.
// =====================================================================
extern "C" __global__ __launch_bounds__(256)
void prep_kernel(const float* __restrict__ Wf1, const float* __restrict__ Wf2,
                 ushort* __restrict__ Wf1t, ushort* __restrict__ Wf2t)
{
  int gid = blockIdx.x * 256 + threadIdx.x;          // 8192 threads
  {
    int k = gid >> 7, n = gid & 127;                 // k 0..63
    float v = (k < G_) ? Wf1[(size_t)k * F_ + n] : 0.f;
    Wf1t[n * 64 + k] = f2bf(v);
  }
  #pragma unroll
  for (int rep = 0; rep < 2; ++rep) {
    int idx = gid + rep * 8192;
    int k = idx >> 7, n = idx & 127;
    Wf2t[n * 128 + k] = f2bf(Wf2[(size_t)k * F_ + n]);
  }
}

// =====================================================================
// K1: filter MLP via bf16 MFMA. 64 rows/block, 4 waves, 16x16x32 tiles.
// =====================================================================
struct __align__(16) SmemF {
  ushort ft[64 * 72];    // (2f-1) bf16, row stride 72 (144B, 16B-aligned)
  ushort h1[64 * 136];   // ssp(layer1) bf16, row stride 136 (272B)
  float  C[64];          // cosine cutoff
};  // 26880 B -> 4+ blocks/CU

extern "C" __global__ __launch_bounds__(256, 4)
void filter_kernel(const float* __restrict__ fij, const float* __restrict__ r_ij,
                   const ushort* __restrict__ Wf1t, const float* __restrict__ bf1,
                   const ushort* __restrict__ Wf2t, const float* __restrict__ bf2p,
                   float* __restrict__ out_W)
{
  __shared__ SmemF sm;
  const int t = threadIdx.x;
  const int lane = t & 63, w = t >> 6;
  const int m0 = w * 16;                 // wave's 16-row M-tile
  const int c16 = lane & 15, q = lane >> 4;
  const size_t Rb = (size_t)blockIdx.x * 64;

  // ---- stage ft = bf16(2*f_ij-1), K padded to 64 ----
  for (int idx = t; idx < 64 * 32; idx += 256) {
    int row = idx >> 5, kp = idx & 31;   // kp: bf16 pair index
    uint pk = 0;
    if (kp < 25) {                       // k0=2kp: 0..48 (pairs cover 0..49)
      float2 v = *(const float2*)(fij + (Rb + row) * G_ + 2 * kp);
      pk = (uint)f2bf(2.f * v.x - 1.f) | ((uint)f2bf(2.f * v.y - 1.f) << 16);
    }
    ((uint*)sm.ft)[row * 36 + kp] = pk;
  }
  if (t < 64) {
    float r = r_ij[Rb + t];
    sm.C[t] = (r < 5.0f) ? 0.5f * (cosf(0.62831853071795864769f * r) + 1.0f) : 0.0f;
  }
  __syncthreads();

  // ---- layer 1: h1 = ssp(ft @ Wf1 + b1), M=64 N=128 K=64 ----
  {
    const char* ap = (const char*)sm.ft + (m0 + c16) * 144 + q * 16;
    short8 a0 = *(const short8*)(ap);
    short8 a1 = *(const short8*)(ap + 64);
    #pragma unroll
    for (int nt = 0; nt < 8; ++nt) {
      int n = nt * 16 + c16;
      const char* bb = (const char*)Wf1t + n * 128 + q * 16;
      short8 b0 = *(const short8*)(bb);
      short8 b1 = *(const short8*)(bb + 64);
      floatx4 acc = {0.f, 0.f, 0.f, 0.f};
      acc = __builtin_amdgcn_mfma_f32_16x16x32_bf16(a0, b0, acc, 0, 0, 0);
      acc = __builtin_amdgcn_mfma_f32_16x16x32_bf16(a1, b1, acc, 0, 0, 0);
      float bias = bf1[n];
      #pragma unroll
      for (int r = 0; r < 4; ++r) {      // C/D: col=lane&15, row=q*4+r
        int row = m0 + q * 4 + r;
        sm.h1[row * 136 + n] = f2bf(ssp(acc[r] + bias));
      }
    }
  }
  __syncthreads();

  // ---- layer 2: W = (h1 @ Wf2 + b2) * C, M=64 N=128 K=128 ----
  {
    short8 a[4];
    const char* ap = (const char*)sm.h1 + (m0 + c16) * 272 + q * 16;
    #pragma unroll
    for (int s = 0; s < 4; ++s) a[s] = *(const short8*)(ap + s * 64);
    #pragma unroll 2
    for (int nt = 0; nt < 8; ++nt) {
      int n = nt * 16 + c16;
      const char* bb = (const char*)Wf2t + n * 256 + q * 16;
      floatx4 acc = {0.f, 0.f, 0.f, 0.f};
      #pragma unroll
      for (int s = 0; s < 4; ++s) {
        short8 b = *(const short8*)(bb + s * 64);
        acc = __builtin_amdgcn_mfma_f32_16x16x32_bf16(a[s], b, acc, 0, 0, 0);
      }
      float bias = bf2p[n];
      #pragma unroll
      for (int r = 0; r < 4; ++r) {
        int row = m0 + q * 4 + r;
        out_W[(Rb + row) * F_ + n] = (acc[r] + bias) * sm.C[row];
      }
    }
  }
}

// =====================================================================
// K0: QKV = x @ {Wq,Wk,Wv}; flat GEMM, 32 rows/block, blockIdx.y picks mat.
// =====================================================================
extern "C" __global__ __launch_bounds__(256, 4)
void qkv_kernel(const float* __restrict__ x,
                const float* __restrict__ Wq, const float* __restrict__ Wk,
                const float* __restrict__ Wv,
                float* __restrict__ Qo, float* __restrict__ Ko, float* __restrict__ Vo)
{
  __shared__ float xs[32 * 128];
  const int t = threadIdx.x;
  const int f = t & 127, h = t >> 7;
  const size_t Rb = (size_t)blockIdx.x * 32;
  const float* W = (blockIdx.y == 0) ? Wq : (blockIdx.y == 1) ? Wk : Wv;
  float* O = (blockIdx.y == 0) ? Qo : (blockIdx.y == 1) ? Ko : Vo;

  {
    const float4* src = (const float4*)(x + Rb * F_);
    float4* dst = (float4*)xs;
    #pragma unroll
    for (int k = 0; k < 4; ++k) dst[t + 256 * k] = src[t + 256 * k];
  }
  __syncthreads();

  float acc[16];
  #pragma unroll
  for (int j = 0; j < 16; ++j) acc[j] = 0.f;
  #pragma unroll
  for (int kc = 0; kc < 4; ++kc) {
    float wr[32];
    #pragma unroll
    for (int kk = 0; kk < 32; ++kk) wr[kk] = W[(size_t)(kc * 32 + kk) * F_ + f];
    #pragma unroll
    for (int j = 0; j < 16; ++j) {
      const float4* xr = (const float4*)&xs[(h * 16 + j) * 128 + kc * 32];
      #pragma unroll
      for (int qq = 0; qq < 8; ++qq) {
        float4 v = xr[qq];
        acc[j] += v.x * wr[qq * 4] + v.y * wr[qq * 4 + 1]
                + v.z * wr[qq * 4 + 2] + v.w * wr[qq * 4 + 3];
      }
    }
  }
  #pragma unroll
  for (int j = 0; j < 16; ++j)
    O[(Rb + h * 16 + j) * F_ + f] = acc[j];
}

// =====================================================================
// K2: wave-per-atom attention. No LDS, no barriers.
// =====================================================================
extern "C" __global__ __launch_bounds__(256, 4)
void attn_kernel(const float* __restrict__ Q, const float* __restrict__ K,
                 const float* __restrict__ V, const float* __restrict__ Wg,
                 const int* __restrict__ nbr, const int* __restrict__ pmask,
                 float* __restrict__ m_pre)
{
  const int t = threadIdx.x;
  const int lane = t & 63, w = t >> 6;
  const int a = blockIdx.x * 4 + w;
  const int b = a >> 11, i = a & 2047;
  const size_t base_nn = (size_t)a * NN;

  int nbrv = (lane < NN) ? nbr[base_nn + lane] : 0;
  int pmv  = (lane < NN) ? pmask[base_nn + lane] : 1;

  float2 q2 = *(const float2*)(Q + (size_t)a * F_ + lane * 2);

  float s_lane = -1e30f;
  #pragma unroll
  for (int n = 0; n < NK; ++n) {
    int src = (n == 0) ? i : __shfl(nbrv, n - 1);
    float2 k2 = *(const float2*)(K + ((size_t)b * NA + src) * F_ + lane * 2);
    float p = q2.x * k2.x + q2.y * k2.y;
    #pragma unroll
    for (int o = 32; o; o >>= 1) p += __shfl_xor(p, o);
    p *= 0.08838834764831845f;
    if (n > 0 && __shfl(pmv, n - 1) == 0) p = -1e9f;
    if (lane == n) s_lane = p;
  }

  float mx = s_lane;
  #pragma unroll
  for (int o = 32; o; o >>= 1) mx = fmaxf(mx, __shfl_xor(mx, o));
  float ev = (lane < NK) ? __expf(s_lane - mx) : 0.f;
  float sum = ev;
  #pragma unroll
  for (int o = 32; o; o >>= 1) sum += __shfl_xor(sum, o);
  float attn_l = ev / sum;

  float2 acc = {0.f, 0.f};
  #pragma unroll 8
  for (int n = 0; n < NK; ++n) {
    float an = __shfl(attn_l, n);
    int src = (n == 0) ? i : __shfl(nbrv, n - 1);
    float2 v2 = *(const float2*)(V + ((size_t)b * NA + src) * F_ + lane * 2);
    float2 w2 = {1.f, 1.f};
    if (n > 0) w2 = *(const float2*)(Wg + (base_nn + n - 1) * F_ + lane * 2);
    acc.x += an * w2.x * v2.x;
    acc.y += an * w2.y * v2.y;
  }
  *(float2*)(m_pre + (size_t)a * F_ + lane * 2) = acc;
}

// =====================================================================
// K3: out_m = ssp(m_pre @ Wo + bo); flat GEMM, 32 rows/block.
// =====================================================================
extern "C" __global__ __launch_bounds__(256, 4)
void out_kernel(const float* __restrict__ m_pre, const float* __restrict__ Wo,
                const float* __restrict__ bo, float* __restrict__ out_m)
{
  __shared__ float xs[32 * 128];
  const int t = threadIdx.x;
  const int f = t & 127, h = t >> 7;
  const size_t Rb = (size_t)blockIdx.x * 32;

  {
    const float4* src = (const float4*)(m_pre + Rb * F_);
    float4* dst = (float4*)xs;
    #pragma unroll
    for (int k = 0; k < 4; ++k) dst[t + 256 * k] = src[t + 256 * k];
  }
  __syncthreads();

  float acc[16];
  float bb = bo[f];
  #pragma unroll
  for (int j = 0; j < 16; ++j) acc[j] = bb;
  #pragma unroll
  for (int kc = 0; kc < 4; ++kc) {
    float wr[32];
    #pragma unroll
    for (int kk = 0; kk < 32; ++kk) wr[kk] = Wo[(size_t)(kc * 32 + kk) * F_ + f];
    #pragma unroll
    for (int j = 0; j < 16; ++j) {
      const float4* xr = (const float4*)&xs[(h * 16 + j) * 128 + kc * 32];
      #pragma unroll
      for (int qq = 0; qq < 8; ++qq) {
        float4 v = xr[qq];
        acc[j] += v.x * wr[qq * 4] + v.y * wr[qq * 4 + 1]
                + v.z * wr[qq * 4 + 2] + v.w * wr[qq * 4 + 3];
      }
    }
  }
  #pragma unroll
  for (int j = 0; j < 16; ++j)
    out_m[(Rb + h * 16 + j) * F_ + f] = ssp(acc[j]);
}

extern "C" void kernel_launch(void* const* d_in, const int* in_sizes, int n_in,
                              void* d_out, int out_size, void* d_ws, size_t ws_size,
                              hipStream_t stream) {
  // inputs: 0=e(unused) 1=x 2=t(unused) 3=r_ij 4=neighbors 5=pairwise_mask 6=f_ij
  //         7=Wf1 8=bf1 9=Wf2 10=bf2 11=Wq 12=Wk 13=Wv 14=Wo 15=bo
  const float* x   = (const float*)d_in[1];
  const float* r   = (const float*)d_in[3];
  const int*  nbr  = (const int*)d_in[4];
  const int*  pmk  = (const int*)d_in[5];
  const float* fij = (const float*)d_in[6];
  const float* Wf1 = (const float*)d_in[7];
  const float* bf1 = (const float*)d_in[8];
  const float* Wf2 = (const float*)d_in[9];
  const float* bf2p= (const float*)d_in[10];
  const float* Wq  = (const float*)d_in[11];
  const float* Wk  = (const float*)d_in[12];
  const float* Wv  = (const float*)d_in[13];
  const float* Wo  = (const float*)d_in[14];
  const float* bo  = (const float*)d_in[15];
  float* out_m = (float*)d_out;                       // [B,Na,F]
  float* out_W = out_m + (size_t)NAT * F_;            // [B,Na,Nn,F]

  // workspace: Q | K | V | m_pre (4 x 2MB) | Wf1t (16KB) | Wf2t (32KB)
  float* Qs = (float*)d_ws;
  float* Ks = Qs + (size_t)NAT * F_;
  float* Vs = Ks + (size_t)NAT * F_;
  float* Ms = Vs + (size_t)NAT * F_;
  ushort* Wf1t = (ushort*)(Ms + (size_t)NAT * F_);
  ushort* Wf2t = Wf1t + 128 * 64;

  hipLaunchKernelGGL(prep_kernel, dim3(32), dim3(256), 0, stream,
                     Wf1, Wf2, Wf1t, Wf2t);
  hipLaunchKernelGGL(qkv_kernel, dim3(NAT / 32, 3), dim3(256), 0, stream,
                     x, Wq, Wk, Wv, Qs, Ks, Vs);
  hipLaunchKernelGGL(filter_kernel, dim3(NROW / 64), dim3(256), 0, stream,
                     fij, r, Wf1t, bf1, Wf2t, bf2p, out_W);
  hipLaunchKernelGGL(attn_kernel, dim3(NAT / 4), dim3(256), 0, stream,
                     Qs, Ks, Vs, out_W, nbr, pmk, Ms);
  hipLaunchKernelGGL(out_kernel, dim3(NAT / 32), dim3(256), 0, stream,
                     Ms, Wo, bo, out_m);
}

// Round 9
// 284.718 us; speedup vs baseline: 27.9507x; 1.0957x over previous
//
#include <hip/hip_runtime.h>

typedef unsigned int uint;
typedef unsigned short ushort;

#define B_  2
#define NA  2048
#define NN  48
#define G_  50
#define F_  128
#define NK  49   // Nn + 1 (self)
#define NROW (B_ * NA * NN)   // 196608 flat filter rows
#define NAT  (B_ * NA)        // 4096 atoms

typedef short short8 __attribute__((ext_vector_type(8)));
typedef float floatx4 __attribute__((ext_vector_type(4)));

__device__ __forceinline__ float ssp(float z) {  // softplus(z)-ln2: fast v_exp/v_log
  return fmaxf(z, 0.f) + __logf(1.f + __expf(-fabsf(z))) - 0.69314718055994531f;
}
__device__ __forceinline__ ushort f2bf(float x) {  // RNE
  union { float f; uint u; } v; v.f = x;
  uint u = v.u;
  u += 0x7fffu + ((u >> 16) & 1u);
  return (ushort)(u >> 16);
}
__device__ __forceinline__ uint pk2bf(float x, float y) {
  return (uint)f2bf(x) | ((uint)f2bf(y) << 16);
}

// =====================================================================
// P: weight prep -> transposed bf16 [n][k] tables (MFMA B-fragments)
//    for filter (Wf1,Wf2), V and O paths. Q/K stay f32.
// =====================================================================
extern "C" __global__ __launch_bounds__(256)
void prep_kernel(const float* __restrict__ Wf1, const float* __restrict__ Wf2,
                 const float* __restrict__ Wv, const float* __restrict__ Wo,
                 ushort* __restrict__ Wf1t, ushort* __restrict__ Wf2t,
                 ushort* __restrict__ Wvt, ushort* __restrict__ Wot)
{
  int gid = blockIdx.x * 256 + threadIdx.x;   // 24576 threads
  if (gid < 8192) {   // Wf1t [128][64], K padded 50->64
    int n = gid >> 6, k = gid & 63;
    Wf1t[gid] = f2bf((k < G_) ? Wf1[(size_t)k * F_ + n] : 0.f);
  }
  for (int idx = gid; idx < 3 * 16384; idx += 24576) {
    int m = idx >> 14, e = idx & 16383;
    int n = e >> 7, k = e & 127;
    const float* src = (m == 0) ? Wf2 : (m == 1) ? Wv : Wo;
    ushort* dst = (m == 0) ? Wf2t : (m == 1) ? Wvt : Wot;
    dst[e] = f2bf(src[(size_t)k * F_ + n]);
  }
}

// =====================================================================
// K0a: Q/K = x @ {Wq,Wk} in f32 VALU (R5/R6-proven structure).
// =====================================================================
extern "C" __global__ __launch_bounds__(256, 4)
void qk_kernel(const float* __restrict__ x,
               const float* __restrict__ Wq, const float* __restrict__ Wk,
               float* __restrict__ Qo, float* __restrict__ Ko)
{
  __shared__ float xs[32 * 128];
  const int t = threadIdx.x;
  const int f = t & 127, h = t >> 7;
  const size_t Rb = (size_t)blockIdx.x * 32;
  const float* W = blockIdx.y ? Wk : Wq;
  float* O = blockIdx.y ? Ko : Qo;

  {
    const float4* src = (const float4*)(x + Rb * F_);
    float4* dst = (float4*)xs;
    #pragma unroll
    for (int k = 0; k < 4; ++k) dst[t + 256 * k] = src[t + 256 * k];
  }
  __syncthreads();

  float acc[16];
  #pragma unroll
  for (int j = 0; j < 16; ++j) acc[j] = 0.f;
  #pragma unroll
  for (int kc = 0; kc < 4; ++kc) {
    float wr[32];
    #pragma unroll
    for (int kk = 0; kk < 32; ++kk) wr[kk] = W[(size_t)(kc * 32 + kk) * F_ + f];
    #pragma unroll
    for (int j = 0; j < 16; ++j) {
      const float4* xr = (const float4*)&xs[(h * 16 + j) * 128 + kc * 32];
      #pragma unroll
      for (int qq = 0; qq < 8; ++qq) {   // wave-uniform b128 broadcasts
        float4 v = xr[qq];
        acc[j] += v.x * wr[qq * 4] + v.y * wr[qq * 4 + 1]
                + v.z * wr[qq * 4 + 2] + v.w * wr[qq * 4 + 3];
      }
    }
  }
  #pragma unroll
  for (int j = 0; j < 16; ++j)
    O[(Rb + h * 16 + j) * F_ + f] = acc[j];
}

// =====================================================================
// K0b: V = x @ Wv via bf16 MFMA (filter-verified fragment pattern).
// =====================================================================
extern "C" __global__ __launch_bounds__(256, 4)
void v_kernel(const float* __restrict__ x, const ushort* __restrict__ Wvt,
              float* __restrict__ Vo)
{
  __shared__ ushort xb[16 * 136];   // row stride 272 B
  const int t = threadIdx.x;
  const int lane = t & 63, w = t >> 6;
  const int c16 = lane & 15, q = lane >> 4;
  const size_t Rb = (size_t)blockIdx.x * 16;

  {
    int row = t >> 4, col = (t & 15) * 8;
    float4 v0 = *(const float4*)(x + (Rb + row) * F_ + col);
    float4 v1 = *(const float4*)(x + (Rb + row) * F_ + col + 4);
    uint4 pk = { pk2bf(v0.x, v0.y), pk2bf(v0.z, v0.w),
                 pk2bf(v1.x, v1.y), pk2bf(v1.z, v1.w) };
    *(uint4*)((char*)xb + row * 272 + col * 2) = pk;
  }
  __syncthreads();

  short8 a[4];
  const char* ap = (const char*)xb + c16 * 272 + q * 16;
  #pragma unroll
  for (int s = 0; s < 4; ++s) a[s] = *(const short8*)(ap + s * 64);

  #pragma unroll
  for (int u = 0; u < 2; ++u) {
    int n = (w * 2 + u) * 16 + c16;
    const char* bb = (const char*)Wvt + n * 256 + q * 16;
    floatx4 acc = {0.f, 0.f, 0.f, 0.f};
    #pragma unroll
    for (int s = 0; s < 4; ++s) {
      short8 b = *(const short8*)(bb + s * 64);
      acc = __builtin_amdgcn_mfma_f32_16x16x32_bf16(a[s], b, acc, 0, 0, 0);
    }
    #pragma unroll
    for (int r = 0; r < 4; ++r)
      Vo[(Rb + q * 4 + r) * F_ + n] = acc[r];
  }
}

// =====================================================================
// K1: filter MLP via bf16 MFMA (R6-verified structure, fast ssp).
// =====================================================================
struct __align__(16) SmemF {
  ushort ft[64 * 72];
  ushort h1[64 * 136];
  float  C[64];
};  // 26880 B

extern "C" __global__ __launch_bounds__(256, 4)
void filter_kernel(const float* __restrict__ fij, const float* __restrict__ r_ij,
                   const ushort* __restrict__ Wf1t, const float* __restrict__ bf1,
                   const ushort* __restrict__ Wf2t, const float* __restrict__ bf2p,
                   float* __restrict__ out_W)
{
  __shared__ SmemF sm;
  const int t = threadIdx.x;
  const int lane = t & 63, w = t >> 6;
  const int m0 = w * 16;
  const int c16 = lane & 15, q = lane >> 4;
  const size_t Rb = (size_t)blockIdx.x * 64;

  for (int idx = t; idx < 64 * 32; idx += 256) {
    int row = idx >> 5, kp = idx & 31;
    uint pk = 0;
    if (kp < 25) {
      float2 v = *(const float2*)(fij + (Rb + row) * G_ + 2 * kp);
      pk = pk2bf(2.f * v.x - 1.f, 2.f * v.y - 1.f);
    }
    ((uint*)sm.ft)[row * 36 + kp] = pk;
  }
  if (t < 64) {
    float r = r_ij[Rb + t];
    sm.C[t] = (r < 5.0f) ? 0.5f * (cosf(0.62831853071795864769f * r) + 1.0f) : 0.0f;
  }
  __syncthreads();

  {  // layer 1: M=64 N=128 K=64
    const char* ap = (const char*)sm.ft + (m0 + c16) * 144 + q * 16;
    short8 a0 = *(const short8*)(ap);
    short8 a1 = *(const short8*)(ap + 64);
    #pragma unroll
    for (int nt = 0; nt < 8; ++nt) {
      int n = nt * 16 + c16;
      const char* bb = (const char*)Wf1t + n * 128 + q * 16;
      short8 b0 = *(const short8*)(bb);
      short8 b1 = *(const short8*)(bb + 64);
      floatx4 acc = {0.f, 0.f, 0.f, 0.f};
      acc = __builtin_amdgcn_mfma_f32_16x16x32_bf16(a0, b0, acc, 0, 0, 0);
      acc = __builtin_amdgcn_mfma_f32_16x16x32_bf16(a1, b1, acc, 0, 0, 0);
      float bias = bf1[n];
      #pragma unroll
      for (int r = 0; r < 4; ++r) {
        int row = m0 + q * 4 + r;
        sm.h1[row * 136 + n] = f2bf(ssp(acc[r] + bias));
      }
    }
  }
  __syncthreads();

  {  // layer 2: M=64 N=128 K=128
    short8 a[4];
    const char* ap = (const char*)sm.h1 + (m0 + c16) * 272 + q * 16;
    #pragma unroll
    for (int s = 0; s < 4; ++s) a[s] = *(const short8*)(ap + s * 64);
    #pragma unroll 2
    for (int nt = 0; nt < 8; ++nt) {
      int n = nt * 16 + c16;
      const char* bb = (const char*)Wf2t + n * 256 + q * 16;
      floatx4 acc = {0.f, 0.f, 0.f, 0.f};
      #pragma unroll
      for (int s = 0; s < 4; ++s) {
        short8 b = *(const short8*)(bb + s * 64);
        acc = __builtin_amdgcn_mfma_f32_16x16x32_bf16(a[s], b, acc, 0, 0, 0);
      }
      float bias = bf2p[n];
      #pragma unroll
      for (int r = 0; r < 4; ++r) {
        int row = m0 + q * 4 + r;
        out_W[(Rb + row) * F_ + n] = (acc[r] + bias) * sm.C[row];
      }
    }
  }
}

// =====================================================================
// K2: wave-per-atom attention — R6-VERIFIED version, verbatim.
//     (R7 half-wave/LDS-staged restructure is the prime suspect for the
//      deterministic Q/K-independent 0.79 failure; reverted.)
// =====================================================================
extern "C" __global__ __launch_bounds__(256, 4)
void attn_kernel(const float* __restrict__ Q, const float* __restrict__ K,
                 const float* __restrict__ V, const float* __restrict__ Wg,
                 const int* __restrict__ nbr, const int* __restrict__ pmask,
                 float* __restrict__ m_pre)
{
  const int t = threadIdx.x;
  const int lane = t & 63, w = t >> 6;
  const int a = blockIdx.x * 4 + w;
  const int b = a >> 11, i = a & 2047;
  const size_t base_nn = (size_t)a * NN;

  int nbrv = (lane < NN) ? nbr[base_nn + lane] : 0;
  int pmv  = (lane < NN) ? pmask[base_nn + lane] : 1;

  float2 q2 = *(const float2*)(Q + (size_t)a * F_ + lane * 2);

  float s_lane = -1e30f;
  #pragma unroll
  for (int n = 0; n < NK; ++n) {
    int src = (n == 0) ? i : __shfl(nbrv, (n > 0) ? n - 1 : 0);
    float2 k2 = *(const float2*)(K + ((size_t)b * NA + src) * F_ + lane * 2);
    float p = q2.x * k2.x + q2.y * k2.y;
    #pragma unroll
    for (int o = 32; o; o >>= 1) p += __shfl_xor(p, o);
    p *= 0.08838834764831845f;
    if (n > 0 && __shfl(pmv, n - 1) == 0) p = -1e9f;
    if (lane == n) s_lane = p;
  }

  float mx = s_lane;
  #pragma unroll
  for (int o = 32; o; o >>= 1) mx = fmaxf(mx, __shfl_xor(mx, o));
  float ev = (lane < NK) ? __expf(s_lane - mx) : 0.f;
  float sum = ev;
  #pragma unroll
  for (int o = 32; o; o >>= 1) sum += __shfl_xor(sum, o);
  float attn_l = ev / sum;

  float2 acc = {0.f, 0.f};
  #pragma unroll 8
  for (int n = 0; n < NK; ++n) {
    float an = __shfl(attn_l, n);
    int src = (n == 0) ? i : __shfl(nbrv, (n > 0) ? n - 1 : 0);
    float2 v2 = *(const float2*)(V + ((size_t)b * NA + src) * F_ + lane * 2);
    float2 w2 = {1.f, 1.f};
    if (n > 0) w2 = *(const float2*)(Wg + (base_nn + n - 1) * F_ + lane * 2);
    acc.x += an * w2.x * v2.x;
    acc.y += an * w2.y * v2.y;
  }
  *(float2*)(m_pre + (size_t)a * F_ + lane * 2) = acc;
}

// =====================================================================
// K3: out_m = ssp(m_pre @ Wo + bo) via MFMA. 16 rows/block.
// =====================================================================
extern "C" __global__ __launch_bounds__(256, 4)
void out_kernel(const float* __restrict__ m_pre, const ushort* __restrict__ Wot,
                const float* __restrict__ bo, float* __restrict__ out_m)
{
  __shared__ ushort xb[16 * 136];
  const int t = threadIdx.x;
  const int lane = t & 63, w = t >> 6;
  const int c16 = lane & 15, q = lane >> 4;
  const size_t Rb = (size_t)blockIdx.x * 16;

  {
    int row = t >> 4, col = (t & 15) * 8;
    float4 v0 = *(const float4*)(m_pre + (Rb + row) * F_ + col);
    float4 v1 = *(const float4*)(m_pre + (Rb + row) * F_ + col + 4);
    uint4 pk = { pk2bf(v0.x, v0.y), pk2bf(v0.z, v0.w),
                 pk2bf(v1.x, v1.y), pk2bf(v1.z, v1.w) };
    *(uint4*)((char*)xb + row * 272 + col * 2) = pk;
  }
  __syncthreads();

  short8 a[4];
  const char* ap = (const char*)xb + c16 * 272 + q * 16;
  #pragma unroll
  for (int s = 0; s < 4; ++s) a[s] = *(const short8*)(ap + s * 64);

  #pragma unroll
  for (int u = 0; u < 2; ++u) {
    int n = (w * 2 + u) * 16 + c16;
    const char* bb = (const char*)Wot + n * 256 + q * 16;
    floatx4 acc = {0.f, 0.f, 0.f, 0.f};
    #pragma unroll
    for (int s = 0; s < 4; ++s) {
      short8 b = *(const short8*)(bb + s * 64);
      acc = __builtin_amdgcn_mfma_f32_16x16x32_bf16(a[s], b, acc, 0, 0, 0);
    }
    float bias = bo[n];
    #pragma unroll
    for (int r = 0; r < 4; ++r)
      out_m[(Rb + q * 4 + r) * F_ + n] = ssp(acc[r] + bias);
  }
}

extern "C" void kernel_launch(void* const* d_in, const int* in_sizes, int n_in,
                              void* d_out, int out_size, void* d_ws, size_t ws_size,
                              hipStream_t stream) {
  // inputs: 0=e(unused) 1=x 2=t(unused) 3=r_ij 4=neighbors 5=pairwise_mask 6=f_ij
  //         7=Wf1 8=bf1 9=Wf2 10=bf2 11=Wq 12=Wk 13=Wv 14=Wo 15=bo
  const float* x   = (const float*)d_in[1];
  const float* r   = (const float*)d_in[3];
  const int*  nbr  = (const int*)d_in[4];
  const int*  pmk  = (const int*)d_in[5];
  const float* fij = (const float*)d_in[6];
  const float* Wf1 = (const float*)d_in[7];
  const float* bf1 = (const float*)d_in[8];
  const float* Wf2 = (const float*)d_in[9];
  const float* bf2p= (const float*)d_in[10];
  const float* Wq  = (const float*)d_in[11];
  const float* Wk  = (const float*)d_in[12];
  const float* Wv  = (const float*)d_in[13];
  const float* Wo  = (const float*)d_in[14];
  const float* bo  = (const float*)d_in[15];
  float* out_m = (float*)d_out;                       // [B,Na,F]
  float* out_W = out_m + (size_t)NAT * F_;            // [B,Na,Nn,F]

  // ws: Q|K|V|m_pre (4x2MB f32) | Wf1t | Wf2t | Wvt | Wot (bf16)
  float* Qs = (float*)d_ws;
  float* Ks = Qs + (size_t)NAT * F_;
  float* Vs = Ks + (size_t)NAT * F_;
  float* Ms = Vs + (size_t)NAT * F_;
  ushort* Wf1t = (ushort*)(Ms + (size_t)NAT * F_);
  ushort* Wf2t = Wf1t + 128 * 64;
  ushort* Wvt  = Wf2t + 128 * 128;
  ushort* Wot  = Wvt  + 128 * 128;

  hipLaunchKernelGGL(prep_kernel, dim3(96), dim3(256), 0, stream,
                     Wf1, Wf2, Wv, Wo, Wf1t, Wf2t, Wvt, Wot);
  hipLaunchKernelGGL(qk_kernel, dim3(NAT / 32, 2), dim3(256), 0, stream,
                     x, Wq, Wk, Qs, Ks);
  hipLaunchKernelGGL(v_kernel, dim3(NAT / 16), dim3(256), 0, stream,
                     x, Wvt, Vs);
  hipLaunchKernelGGL(filter_kernel, dim3(NROW / 64), dim3(256), 0, stream,
                     fij, r, Wf1t, bf1, Wf2t, bf2p, out_W);
  hipLaunchKernelGGL(attn_kernel, dim3(NAT / 4), dim3(256), 0, stream,
                     Qs, Ks, Vs, out_W, nbr, pmk, Ms);
  hipLaunchKernelGGL(out_kernel, dim3(NAT / 16), dim3(256), 0, stream,
                     Ms, Wot, bo, out_m);
}